// Round 12
// baseline (446.134 us; speedup 1.0000x reference)
//
#include <hip/hip_runtime.h>
#include <math.h>

#define NUM_USERS 100000
#define NUM_ITEMS 200000
#define N_NODES   300000   // NUM_USERS + NUM_ITEMS
#define EMB       64
#define NUM_INTER 1000000
#define N_EDGES   (2 * NUM_INTER)
#define MAX_SLOTS (N_EDGES + 3 * N_NODES + 16)   // rows padded to multiple of 4
#define BATCH     16384
#define SCAN_BLOCK 1024

typedef float vfloat4 __attribute__((ext_vector_type(4)));
typedef int   vint4   __attribute__((ext_vector_type(4)));

// ---------- degree + packed rank (ushort2 in a uint) ----------
__global__ void degree_rank_k(const int* __restrict__ iu, const int* __restrict__ ii,
                              int* __restrict__ deg, unsigned* __restrict__ rr) {
    int e = blockIdx.x * blockDim.x + threadIdx.x;
    if (e < NUM_INTER) {
        int r0 = atomicAdd(&deg[iu[e]], 1);
        int r1 = atomicAdd(&deg[NUM_USERS + ii[e]], 1);
        rr[e] = (unsigned)(r0 | (r1 << 16));   // max degree << 65536
    }
}

// ---------- per-node factors + padded degree + per-block partial sums ----------
__global__ void fact_sum_k(const int* __restrict__ deg, float* __restrict__ dinv,
                           float* __restrict__ d2, float* __restrict__ rcp,
                           int* __restrict__ pdeg, int* __restrict__ bsum) {
    __shared__ int lds[SCAN_BLOCK];
    int g = blockIdx.x * SCAN_BLOCK + threadIdx.x;
    int p = 0;
    if (g < N_NODES) {
        int d = deg[g];
        float fd = (float)d;
        dinv[g] = (d > 0) ? (1.0f / sqrtf(fd)) : 0.0f;
        d2[g]   = (d > 0) ? (1.0f / fd) : 0.0f;
        rcp[g]  = (d > 0) ? sqrtf(fd) : 0.0f;
        p = (d + 3) & ~3;
        pdeg[g] = p;
    }
    lds[threadIdx.x] = p;
    __syncthreads();
    for (int s = SCAN_BLOCK / 2; s > 0; s >>= 1) {
        if (threadIdx.x < s) lds[threadIdx.x] += lds[threadIdx.x + s];
        __syncthreads();
    }
    if (threadIdx.x == 0) bsum[blockIdx.x] = lds[0];
}

// ---------- single-block: scan bsum + softmax(layer_w) + zero dummy rows + count=0 ----------
__global__ void mid_k(int* __restrict__ bsum, int nb,
                      const float* __restrict__ lw, float* __restrict__ w,
                      float* __restrict__ zA, float* __restrict__ zB,
                      int* __restrict__ count) {
    __shared__ int lds[512];
    int t = threadIdx.x;
    int v = (t < nb) ? bsum[t] : 0;
    lds[t] = v;
    __syncthreads();
    for (int ofs = 1; ofs < 512; ofs <<= 1) {
        int x = (t >= ofs) ? lds[t - ofs] : 0;
        __syncthreads();
        lds[t] += x;
        __syncthreads();
    }
    if (t < nb) bsum[t] = lds[t] - v;   // exclusive
    if (t < EMB) {
        zA[(size_t)N_NODES * EMB + t] = 0.0f;
        zB[(size_t)N_NODES * EMB + t] = 0.0f;
    }
    if (t == 0) {
        count[0] = 0;
        float a = lw[0], b = lw[1], c = lw[2], d = lw[3];
        float m = fmaxf(fmaxf(a, b), fmaxf(c, d));
        float e0 = expf(a - m), e1 = expf(b - m), e2 = expf(c - m), e3 = expf(d - m);
        float s = e0 + e1 + e2 + e3;
        w[0] = e0 / s; w[1] = e1 / s; w[2] = e2 / s; w[3] = e3 / s;
    }
}

__global__ void scan_block_k(const int* __restrict__ v, const int* __restrict__ bsum,
                             int* __restrict__ row_start, int n) {
    __shared__ int lds[SCAN_BLOCK];
    int g = blockIdx.x * SCAN_BLOCK + threadIdx.x;
    int x = (g < n) ? v[g] : 0;
    lds[threadIdx.x] = x;
    __syncthreads();
    for (int ofs = 1; ofs < SCAN_BLOCK; ofs <<= 1) {
        int y = (threadIdx.x >= ofs) ? lds[threadIdx.x - ofs] : 0;
        __syncthreads();
        lds[threadIdx.x] += y;
        __syncthreads();
    }
    if (g < n) row_start[g] = bsum[blockIdx.x] + lds[threadIdx.x] - x;  // exclusive
    if (g == n - 1) row_start[n] = bsum[blockIdx.x] + lds[threadIdx.x]; // inclusive total
}

// ---------- CSR fill: atomic-free — slot = row_start + precomputed rank ----------
__global__ void fill_csr_k(const int* __restrict__ iu, const int* __restrict__ ii,
                           const unsigned* __restrict__ rr,
                           const int* __restrict__ row_start, int* __restrict__ nbr) {
    int e = blockIdx.x * blockDim.x + threadIdx.x;
    if (e < NUM_INTER) {
        int u  = iu[e];
        int it = NUM_USERS + ii[e];
        unsigned r = rr[e];
        nbr[row_start[u]  + (int)(r & 0xffffu)] = it;
        nbr[row_start[it] + (int)(r >> 16)]     = u;
    }
}

// ---------- mark the needed-z2 set: queried nodes + their row neighbors ----------
__global__ void mark_k(const int* __restrict__ uid, const int* __restrict__ iid,
                       const int* __restrict__ row_start, const int* __restrict__ deg,
                       const int* __restrict__ nbr, int* __restrict__ flag) {
    int t = blockIdx.x * blockDim.x + threadIdx.x;
    if (t >= BATCH * 2) return;
    int slot = t >> 1;
    int node = (t & 1) ? (NUM_USERS + iid[slot]) : uid[slot];
    flag[node] = 1;
    int beg = row_start[node];
    int lim = beg + deg[node];
    for (int j = beg; j < lim; ++j) flag[nbr[j]] = 1;
}

// ---------- compact flagged nodes to a dense list (per-wave aggregated atomics) ----------
__global__ void compact_k(const int* __restrict__ flag, int* __restrict__ list,
                          int* __restrict__ count) {
    int n = blockIdx.x * blockDim.x + threadIdx.x;
    if (n < N_NODES && flag[n]) {
        list[atomicAdd(count, 1)] = n;   // compiler wave-aggregates (m20)
    }
}

// ---------- prop layer 1 (fused input scaling): z1[v] = d2[v] * sum dinv[n]*emb[n] ----------
// rows padded to x4; unroll-8 reads up to 4 slots past the row (masked; +16 headroom).
__global__ void prop_first_k(const int* __restrict__ row_start, const int* __restrict__ nbr,
                             const int* __restrict__ deg,
                             const float* __restrict__ dinv, const float* __restrict__ d2,
                             const float* __restrict__ ue, const float* __restrict__ ie,
                             float* __restrict__ out) {
    int t = blockIdx.x * blockDim.x + threadIdx.x;
    int node = t >> 4;
    int q = t & 15;
    if (node >= N_NODES) return;
    int beg = row_start[node], end = row_start[node + 1];
    int lim = beg + deg[node];
    const float4* u4 = (const float4*)ue;
    const float4* i4 = (const float4*)ie;
    float4 acc = make_float4(0.f, 0.f, 0.f, 0.f);
    for (int j = beg; j < end; j += 8) {
        vint4 na = __builtin_nontemporal_load((const vint4*)(nbr + j));
        vint4 nb = __builtin_nontemporal_load((const vint4*)(nbr + j + 4));
        #pragma unroll
        for (int k = 0; k < 8; ++k) {
            bool valid = (j + k < lim);
            int id = valid ? ((k < 4) ? na[k] : nb[k - 4]) : 0;
            float w = valid ? dinv[id] : 0.0f;
            const float4* src = (id < NUM_USERS) ? (u4 + (size_t)id * 16)
                                                 : (i4 + (size_t)(id - NUM_USERS) * 16);
            float4 g = src[q];
            acc.x += w * g.x; acc.y += w * g.y; acc.z += w * g.z; acc.w += w * g.w;
        }
    }
    float s = d2[node];
    vfloat4 r = { s * acc.x, s * acc.y, s * acc.z, s * acc.w };
    __builtin_nontemporal_store(r, (vfloat4*)out + (size_t)node * 16 + q);
}

// ---------- prop layer 2 over the compacted needed set ----------
__global__ void prop_compact_k(const int* __restrict__ list, const int* __restrict__ count,
                               const int* __restrict__ row_start, const int* __restrict__ nbr,
                               const int* __restrict__ deg, const float* __restrict__ d2,
                               const float* __restrict__ in, float* __restrict__ out) {
    int t = blockIdx.x * blockDim.x + threadIdx.x;
    int li = t >> 4;
    int q = t & 15;
    if (li >= count[0]) return;
    int node = list[li];
    int beg = row_start[node], end = row_start[node + 1];
    int lim = beg + deg[node];
    const float4* in4 = (const float4*)in;
    float4 acc = make_float4(0.f, 0.f, 0.f, 0.f);
    for (int j = beg; j < end; j += 8) {
        vint4 na = __builtin_nontemporal_load((const vint4*)(nbr + j));
        vint4 nb = __builtin_nontemporal_load((const vint4*)(nbr + j + 4));
        #pragma unroll
        for (int k = 0; k < 8; ++k) {
            int id = (j + k < lim) ? ((k < 4) ? na[k] : nb[k - 4]) : N_NODES;
            float4 g = in4[(size_t)id * 16 + q];
            acc.x += g.x; acc.y += g.y; acc.z += g.z; acc.w += g.w;
        }
    }
    float s = d2[node];
    vfloat4 r = { s * acc.x, s * acc.y, s * acc.z, s * acc.w };
    __builtin_nontemporal_store(r, (vfloat4*)out + (size_t)node * 16 + q);
}

// ---------- fused epilogue: layer-3 pull at queried nodes + layers 0-2 + dot ----------
__global__ void fused_score_k(const int* __restrict__ row_start, const int* __restrict__ nbr,
                              const int* __restrict__ deg,
                              const float* __restrict__ dinv, const float* __restrict__ rcp,
                              const float* __restrict__ ue, const float* __restrict__ ie,
                              const float* __restrict__ z1, const float* __restrict__ z2,
                              const int* __restrict__ uid, const int* __restrict__ iid,
                              const float* __restrict__ w4, float* __restrict__ out) {
    int t = blockIdx.x * blockDim.x + threadIdx.x;
    int slot = t >> 5;
    if (slot >= BATCH) return;
    int within = t & 31;
    int side = within >> 4;
    int q = within & 15;

    int node;
    const float4* erow;
    if (side == 0) {
        int u = uid[slot];
        node = u;
        erow = (const float4*)ue + (size_t)u * 16;
    } else {
        int ii_ = iid[slot];
        node = NUM_USERS + ii_;
        erow = (const float4*)ie + (size_t)ii_ * 16;
    }

    float w0 = w4[0], w1 = w4[1], w2 = w4[2], w3 = w4[3];
    int beg = row_start[node], end = row_start[node + 1];
    int lim = beg + deg[node];
    const float4* z2v = (const float4*)z2;

    float4 acc = make_float4(0.f, 0.f, 0.f, 0.f);
    for (int j = beg; j < end; j += 8) {
        vint4 na = __builtin_nontemporal_load((const vint4*)(nbr + j));
        vint4 nb = __builtin_nontemporal_load((const vint4*)(nbr + j + 4));
        #pragma unroll
        for (int k = 0; k < 8; ++k) {
            int id = (j + k < lim) ? ((k < 4) ? na[k] : nb[k - 4]) : N_NODES;
            float4 g = z2v[(size_t)id * 16 + q];
            acc.x += g.x; acc.y += g.y; acc.z += g.z; acc.w += g.w;
        }
    }

    float r  = rcp[node];
    float di = dinv[node];
    float4 e  = erow[q];
    float4 a1 = ((const float4*)z1)[(size_t)node * 16 + q];
    float4 a2 = z2v[(size_t)node * 16 + q];

    float4 f;
    f.x = w0 * e.x + r * (w1 * a1.x + w2 * a2.x) + w3 * di * acc.x;
    f.y = w0 * e.y + r * (w1 * a1.y + w2 * a2.y) + w3 * di * acc.y;
    f.z = w0 * e.z + r * (w1 * a1.z + w2 * a2.z) + w3 * di * acc.z;
    f.w = w0 * e.w + r * (w1 * a1.w + w2 * a2.w) + w3 * di * acc.w;

    float4 o;
    o.x = __shfl_xor(f.x, 16);
    o.y = __shfl_xor(f.y, 16);
    o.z = __shfl_xor(f.z, 16);
    o.w = __shfl_xor(f.w, 16);

    float p = f.x * o.x + f.y * o.y + f.z * o.z + f.w * o.w;
    p += __shfl_xor(p, 1);
    p += __shfl_xor(p, 2);
    p += __shfl_xor(p, 4);
    p += __shfl_xor(p, 8);

    if (within == 0) out[slot] = p;
}

// ---------- launch ----------

extern "C" void kernel_launch(void* const* d_in, const int* in_sizes, int n_in,
                              void* d_out, int out_size, void* d_ws, size_t ws_size,
                              hipStream_t stream) {
    const float* user_emb = (const float*)d_in[0];
    const float* item_emb = (const float*)d_in[1];
    const float* layer_w  = (const float*)d_in[2];
    const int*   inter_u  = (const int*)d_in[3];
    const int*   inter_i  = (const int*)d_in[4];
    const int*   user_ids = (const int*)d_in[5];
    const int*   item_ids = (const int*)d_in[6];
    float* out = (float*)d_out;

    char* base = (char*)d_ws;
    size_t off = 0;
    auto alloc = [&](size_t bytes) -> char* {
        char* p = base + off;
        off = (off + bytes + 255) & ~(size_t)255;
        return p;
    };
    float*    w4        = (float*)   alloc(4 * sizeof(float));
    int*      count     = (int*)     alloc(sizeof(int));
    int*      deg       = (int*)     alloc((size_t)N_NODES * sizeof(int));
    int*      pdeg      = (int*)     alloc((size_t)N_NODES * sizeof(int));
    float*    dinv      = (float*)   alloc((size_t)N_NODES * sizeof(float));
    float*    d2        = (float*)   alloc((size_t)N_NODES * sizeof(float));
    float*    rcp       = (float*)   alloc((size_t)N_NODES * sizeof(float));
    int*      row_start = (int*)     alloc(((size_t)N_NODES + 1) * sizeof(int));
    int*      bsum      = (int*)     alloc(512 * sizeof(int));
    unsigned* rr        = (unsigned*)alloc((size_t)NUM_INTER * sizeof(unsigned));
    int*      csr_nbr   = (int*)     alloc((size_t)MAX_SLOTS * sizeof(int));
    int*      flag      = (int*)     alloc((size_t)N_NODES * sizeof(int));
    int*      list      = (int*)     alloc((size_t)N_NODES * sizeof(int));
    float*    zA        = (float*)   alloc(((size_t)N_NODES + 1) * EMB * sizeof(float));
    float*    zB        = (float*)   alloc(((size_t)N_NODES + 1) * EMB * sizeof(float));

    const int nscan_blocks = (N_NODES + SCAN_BLOCK - 1) / SCAN_BLOCK;   // 293

    // 1. degrees + packed ranks
    hipMemsetAsync(deg, 0, (size_t)N_NODES * sizeof(int), stream);
    hipMemsetAsync(flag, 0, (size_t)N_NODES * sizeof(int), stream);
    degree_rank_k<<<(NUM_INTER + 255) / 256, 256, 0, stream>>>(inter_u, inter_i, deg, rr);

    // 2. per-node factors + scan stage 1 (fused)
    fact_sum_k<<<nscan_blocks, SCAN_BLOCK, 0, stream>>>(deg, dinv, d2, rcp, pdeg, bsum);

    // 3. scan stage 2 + softmax + dummy-row zeroing + count=0 (single block, fused)
    mid_k<<<1, 512, 0, stream>>>(bsum, nscan_blocks, layer_w, w4, zA, zB, count);

    // 4. scan stage 3 -> row_start
    scan_block_k<<<nscan_blocks, SCAN_BLOCK, 0, stream>>>(pdeg, bsum, row_start, N_NODES);

    // 5. CSR fill — zero atomics, 2M plain 4B random stores
    fill_csr_k<<<(NUM_INTER + 255) / 256, 256, 0, stream>>>(
        inter_u, inter_i, rr, row_start, csr_nbr);

    // 6. mark + compact the needed-z2 set (queried nodes + their neighbors)
    mark_k<<<(BATCH * 2 + 255) / 256, 256, 0, stream>>>(
        user_ids, item_ids, row_start, deg, csr_nbr, flag);
    compact_k<<<(N_NODES + 255) / 256, 256, 0, stream>>>(flag, list, count);

    // 7. layer 1 full (z1 needed nearly everywhere): zB = z1
    const int per_node_blocks = (N_NODES * 16 + 255) / 256;
    prop_first_k<<<per_node_blocks, 256, 0, stream>>>(
        row_start, csr_nbr, deg, dinv, d2, user_emb, item_emb, zB);

    // 8. layer 2 over compacted list only: zA = z2 (worst-case grid; excess waves
    //    exit on the hot count[0] check)
    prop_compact_k<<<per_node_blocks, 256, 0, stream>>>(
        list, count, row_start, csr_nbr, deg, d2, zB, zA);

    // 9. fused: layer-3 pull at queried nodes + layer 0-2 terms + dot product
    fused_score_k<<<(BATCH * 32 + 255) / 256, 256, 0, stream>>>(
        row_start, csr_nbr, deg, dinv, rcp, user_emb, item_emb,
        zB /*z1*/, zA /*z2*/, user_ids, item_ids, w4, out);
}

// Round 13
// 401.569 us; speedup vs baseline: 1.1110x; 1.1110x over previous
//
#include <hip/hip_runtime.h>
#include <math.h>

#define NUM_USERS 100000
#define NUM_ITEMS 200000
#define N_NODES   300000   // NUM_USERS + NUM_ITEMS
#define EMB       64
#define NUM_INTER 1000000
#define N_EDGES   (2 * NUM_INTER)
#define MAX_SLOTS (N_EDGES + 3 * N_NODES + 16)   // rows padded to multiple of 4
#define BATCH     16384
#define SCAN_BLOCK 1024

typedef float vfloat4 __attribute__((ext_vector_type(4)));
typedef int   vint4   __attribute__((ext_vector_type(4)));

// ---------- degree + packed rank (ushort2 in a uint) ----------
__global__ void degree_rank_k(const int* __restrict__ iu, const int* __restrict__ ii,
                              int* __restrict__ deg, unsigned* __restrict__ rr) {
    int e = blockIdx.x * blockDim.x + threadIdx.x;
    if (e < NUM_INTER) {
        int r0 = atomicAdd(&deg[iu[e]], 1);
        int r1 = atomicAdd(&deg[NUM_USERS + ii[e]], 1);
        rr[e] = (unsigned)(r0 | (r1 << 16));   // max degree << 65536
    }
}

// ---------- per-node factors + padded degree + per-block partial sums ----------
__global__ void fact_sum_k(const int* __restrict__ deg, float* __restrict__ dinv,
                           float* __restrict__ d2, float* __restrict__ rcp,
                           int* __restrict__ pdeg, int* __restrict__ bsum) {
    __shared__ int lds[SCAN_BLOCK];
    int g = blockIdx.x * SCAN_BLOCK + threadIdx.x;
    int p = 0;
    if (g < N_NODES) {
        int d = deg[g];
        float fd = (float)d;
        dinv[g] = (d > 0) ? (1.0f / sqrtf(fd)) : 0.0f;
        d2[g]   = (d > 0) ? (1.0f / fd) : 0.0f;
        rcp[g]  = (d > 0) ? sqrtf(fd) : 0.0f;
        p = (d + 3) & ~3;
        pdeg[g] = p;
    }
    lds[threadIdx.x] = p;
    __syncthreads();
    for (int s = SCAN_BLOCK / 2; s > 0; s >>= 1) {
        if (threadIdx.x < s) lds[threadIdx.x] += lds[threadIdx.x + s];
        __syncthreads();
    }
    if (threadIdx.x == 0) bsum[blockIdx.x] = lds[0];
}

// ---------- single-block: scan bsum + softmax(layer_w) + zero dummy rows ----------
__global__ void mid_k(int* __restrict__ bsum, int nb,
                      const float* __restrict__ lw, float* __restrict__ w,
                      float* __restrict__ zA, float* __restrict__ zB) {
    __shared__ int lds[512];
    int t = threadIdx.x;
    int v = (t < nb) ? bsum[t] : 0;
    lds[t] = v;
    __syncthreads();
    for (int ofs = 1; ofs < 512; ofs <<= 1) {
        int x = (t >= ofs) ? lds[t - ofs] : 0;
        __syncthreads();
        lds[t] += x;
        __syncthreads();
    }
    if (t < nb) bsum[t] = lds[t] - v;   // exclusive
    if (t < EMB) {
        zA[(size_t)N_NODES * EMB + t] = 0.0f;
        zB[(size_t)N_NODES * EMB + t] = 0.0f;
    }
    if (t == 0) {
        float a = lw[0], b = lw[1], c = lw[2], d = lw[3];
        float m = fmaxf(fmaxf(a, b), fmaxf(c, d));
        float e0 = expf(a - m), e1 = expf(b - m), e2 = expf(c - m), e3 = expf(d - m);
        float s = e0 + e1 + e2 + e3;
        w[0] = e0 / s; w[1] = e1 / s; w[2] = e2 / s; w[3] = e3 / s;
    }
}

__global__ void scan_block_k(const int* __restrict__ v, const int* __restrict__ bsum,
                             int* __restrict__ row_start, int n) {
    __shared__ int lds[SCAN_BLOCK];
    int g = blockIdx.x * SCAN_BLOCK + threadIdx.x;
    int x = (g < n) ? v[g] : 0;
    lds[threadIdx.x] = x;
    __syncthreads();
    for (int ofs = 1; ofs < SCAN_BLOCK; ofs <<= 1) {
        int y = (threadIdx.x >= ofs) ? lds[threadIdx.x - ofs] : 0;
        __syncthreads();
        lds[threadIdx.x] += y;
        __syncthreads();
    }
    if (g < n) row_start[g] = bsum[blockIdx.x] + lds[threadIdx.x] - x;  // exclusive
    if (g == n - 1) row_start[n] = bsum[blockIdx.x] + lds[threadIdx.x]; // inclusive total
}

// ---------- CSR fill: atomic-free — slot = row_start + precomputed rank ----------
__global__ void fill_csr_k(const int* __restrict__ iu, const int* __restrict__ ii,
                           const unsigned* __restrict__ rr,
                           const int* __restrict__ row_start, int* __restrict__ nbr) {
    int e = blockIdx.x * blockDim.x + threadIdx.x;
    if (e < NUM_INTER) {
        int u  = iu[e];
        int it = NUM_USERS + ii[e];
        unsigned r = rr[e];
        nbr[row_start[u]  + (int)(r & 0xffffu)] = it;
        nbr[row_start[it] + (int)(r >> 16)]     = u;
    }
}

// ---------- mark the needed-z2 set: queried nodes + their row neighbors ----------
__global__ void mark_k(const int* __restrict__ uid, const int* __restrict__ iid,
                       const int* __restrict__ row_start, const int* __restrict__ deg,
                       const int* __restrict__ nbr, int* __restrict__ flag) {
    int t = blockIdx.x * blockDim.x + threadIdx.x;
    if (t >= BATCH * 2) return;
    int slot = t >> 1;
    int node = (t & 1) ? (NUM_USERS + iid[slot]) : uid[slot];
    flag[node] = 1;
    int beg = row_start[node];
    int lim = beg + deg[node];
    for (int j = beg; j < lim; ++j) flag[nbr[j]] = 1;
}

// ---------- prop layer 1 (fused input scaling): z1[v] = d2[v] * sum dinv[n]*emb[n] ----------
// rows padded to x4; unroll-8 reads up to 4 slots past the row (masked; +16 headroom).
__global__ void prop_first_k(const int* __restrict__ row_start, const int* __restrict__ nbr,
                             const int* __restrict__ deg,
                             const float* __restrict__ dinv, const float* __restrict__ d2,
                             const float* __restrict__ ue, const float* __restrict__ ie,
                             float* __restrict__ out) {
    int t = blockIdx.x * blockDim.x + threadIdx.x;
    int node = t >> 4;
    int q = t & 15;
    if (node >= N_NODES) return;
    int beg = row_start[node], end = row_start[node + 1];
    int lim = beg + deg[node];
    const float4* u4 = (const float4*)ue;
    const float4* i4 = (const float4*)ie;
    float4 acc = make_float4(0.f, 0.f, 0.f, 0.f);
    for (int j = beg; j < end; j += 8) {
        vint4 na = __builtin_nontemporal_load((const vint4*)(nbr + j));
        vint4 nb = __builtin_nontemporal_load((const vint4*)(nbr + j + 4));
        #pragma unroll
        for (int k = 0; k < 8; ++k) {
            bool valid = (j + k < lim);
            int id = valid ? ((k < 4) ? na[k] : nb[k - 4]) : 0;
            float w = valid ? dinv[id] : 0.0f;
            const float4* src = (id < NUM_USERS) ? (u4 + (size_t)id * 16)
                                                 : (i4 + (size_t)(id - NUM_USERS) * 16);
            float4 g = src[q];
            acc.x += w * g.x; acc.y += w * g.y; acc.z += w * g.z; acc.w += w * g.w;
        }
    }
    float s = d2[node];
    vfloat4 r = { s * acc.x, s * acc.y, s * acc.z, s * acc.w };
    __builtin_nontemporal_store(r, (vfloat4*)out + (size_t)node * 16 + q);
}

// ---------- prop layer 2 (node-ordered, flag-masked): z2[v] = d2[v] * sum z1[n] ----------
__global__ void prop_masked_k(const int* __restrict__ row_start, const int* __restrict__ nbr,
                              const int* __restrict__ deg, const float* __restrict__ d2,
                              const int* __restrict__ flag,
                              const float* __restrict__ in, float* __restrict__ out) {
    int t = blockIdx.x * blockDim.x + threadIdx.x;
    int node = t >> 4;
    int q = t & 15;
    if (node >= N_NODES) return;
    if (!flag[node]) return;   // z2 never read at unflagged nodes
    int beg = row_start[node], end = row_start[node + 1];
    int lim = beg + deg[node];
    const float4* in4 = (const float4*)in;
    float4 acc = make_float4(0.f, 0.f, 0.f, 0.f);
    for (int j = beg; j < end; j += 8) {
        vint4 na = __builtin_nontemporal_load((const vint4*)(nbr + j));
        vint4 nb = __builtin_nontemporal_load((const vint4*)(nbr + j + 4));
        #pragma unroll
        for (int k = 0; k < 8; ++k) {
            int id = (j + k < lim) ? ((k < 4) ? na[k] : nb[k - 4]) : N_NODES;
            float4 g = in4[(size_t)id * 16 + q];
            acc.x += g.x; acc.y += g.y; acc.z += g.z; acc.w += g.w;
        }
    }
    float s = d2[node];
    vfloat4 r = { s * acc.x, s * acc.y, s * acc.z, s * acc.w };
    __builtin_nontemporal_store(r, (vfloat4*)out + (size_t)node * 16 + q);
}

// ---------- fused epilogue: layer-3 pull at queried nodes + layers 0-2 + dot ----------
__global__ void fused_score_k(const int* __restrict__ row_start, const int* __restrict__ nbr,
                              const int* __restrict__ deg,
                              const float* __restrict__ dinv, const float* __restrict__ rcp,
                              const float* __restrict__ ue, const float* __restrict__ ie,
                              const float* __restrict__ z1, const float* __restrict__ z2,
                              const int* __restrict__ uid, const int* __restrict__ iid,
                              const float* __restrict__ w4, float* __restrict__ out) {
    int t = blockIdx.x * blockDim.x + threadIdx.x;
    int slot = t >> 5;
    if (slot >= BATCH) return;
    int within = t & 31;
    int side = within >> 4;
    int q = within & 15;

    int node;
    const float4* erow;
    if (side == 0) {
        int u = uid[slot];
        node = u;
        erow = (const float4*)ue + (size_t)u * 16;
    } else {
        int ii_ = iid[slot];
        node = NUM_USERS + ii_;
        erow = (const float4*)ie + (size_t)ii_ * 16;
    }

    float w0 = w4[0], w1 = w4[1], w2 = w4[2], w3 = w4[3];
    int beg = row_start[node], end = row_start[node + 1];
    int lim = beg + deg[node];
    const float4* z2v = (const float4*)z2;

    float4 acc = make_float4(0.f, 0.f, 0.f, 0.f);
    for (int j = beg; j < end; j += 8) {
        vint4 na = __builtin_nontemporal_load((const vint4*)(nbr + j));
        vint4 nb = __builtin_nontemporal_load((const vint4*)(nbr + j + 4));
        #pragma unroll
        for (int k = 0; k < 8; ++k) {
            int id = (j + k < lim) ? ((k < 4) ? na[k] : nb[k - 4]) : N_NODES;
            float4 g = z2v[(size_t)id * 16 + q];
            acc.x += g.x; acc.y += g.y; acc.z += g.z; acc.w += g.w;
        }
    }

    float r  = rcp[node];
    float di = dinv[node];
    float4 e  = erow[q];
    float4 a1 = ((const float4*)z1)[(size_t)node * 16 + q];
    float4 a2 = z2v[(size_t)node * 16 + q];

    float4 f;
    f.x = w0 * e.x + r * (w1 * a1.x + w2 * a2.x) + w3 * di * acc.x;
    f.y = w0 * e.y + r * (w1 * a1.y + w2 * a2.y) + w3 * di * acc.y;
    f.z = w0 * e.z + r * (w1 * a1.z + w2 * a2.z) + w3 * di * acc.z;
    f.w = w0 * e.w + r * (w1 * a1.w + w2 * a2.w) + w3 * di * acc.w;

    float4 o;
    o.x = __shfl_xor(f.x, 16);
    o.y = __shfl_xor(f.y, 16);
    o.z = __shfl_xor(f.z, 16);
    o.w = __shfl_xor(f.w, 16);

    float p = f.x * o.x + f.y * o.y + f.z * o.z + f.w * o.w;
    p += __shfl_xor(p, 1);
    p += __shfl_xor(p, 2);
    p += __shfl_xor(p, 4);
    p += __shfl_xor(p, 8);

    if (within == 0) out[slot] = p;
}

// ---------- launch ----------

extern "C" void kernel_launch(void* const* d_in, const int* in_sizes, int n_in,
                              void* d_out, int out_size, void* d_ws, size_t ws_size,
                              hipStream_t stream) {
    const float* user_emb = (const float*)d_in[0];
    const float* item_emb = (const float*)d_in[1];
    const float* layer_w  = (const float*)d_in[2];
    const int*   inter_u  = (const int*)d_in[3];
    const int*   inter_i  = (const int*)d_in[4];
    const int*   user_ids = (const int*)d_in[5];
    const int*   item_ids = (const int*)d_in[6];
    float* out = (float*)d_out;

    char* base = (char*)d_ws;
    size_t off = 0;
    auto alloc = [&](size_t bytes) -> char* {
        char* p = base + off;
        off = (off + bytes + 255) & ~(size_t)255;
        return p;
    };
    float*    w4        = (float*)   alloc(4 * sizeof(float));
    int*      deg       = (int*)     alloc((size_t)N_NODES * sizeof(int));
    int*      pdeg      = (int*)     alloc((size_t)N_NODES * sizeof(int));
    float*    dinv      = (float*)   alloc((size_t)N_NODES * sizeof(float));
    float*    d2        = (float*)   alloc((size_t)N_NODES * sizeof(float));
    float*    rcp       = (float*)   alloc((size_t)N_NODES * sizeof(float));
    int*      row_start = (int*)     alloc(((size_t)N_NODES + 1) * sizeof(int));
    int*      bsum      = (int*)     alloc(512 * sizeof(int));
    unsigned* rr        = (unsigned*)alloc((size_t)NUM_INTER * sizeof(unsigned));
    int*      csr_nbr   = (int*)     alloc((size_t)MAX_SLOTS * sizeof(int));
    int*      flag      = (int*)     alloc((size_t)N_NODES * sizeof(int));
    float*    zA        = (float*)   alloc(((size_t)N_NODES + 1) * EMB * sizeof(float));
    float*    zB        = (float*)   alloc(((size_t)N_NODES + 1) * EMB * sizeof(float));

    const int nscan_blocks = (N_NODES + SCAN_BLOCK - 1) / SCAN_BLOCK;   // 293

    // 1. degrees + packed ranks
    hipMemsetAsync(deg, 0, (size_t)N_NODES * sizeof(int), stream);
    hipMemsetAsync(flag, 0, (size_t)N_NODES * sizeof(int), stream);
    degree_rank_k<<<(NUM_INTER + 255) / 256, 256, 0, stream>>>(inter_u, inter_i, deg, rr);

    // 2. per-node factors + scan stage 1 (fused)
    fact_sum_k<<<nscan_blocks, SCAN_BLOCK, 0, stream>>>(deg, dinv, d2, rcp, pdeg, bsum);

    // 3. scan stage 2 + softmax + dummy-row zeroing (single block, fused)
    mid_k<<<1, 512, 0, stream>>>(bsum, nscan_blocks, layer_w, w4, zA, zB);

    // 4. scan stage 3 -> row_start
    scan_block_k<<<nscan_blocks, SCAN_BLOCK, 0, stream>>>(pdeg, bsum, row_start, N_NODES);

    // 5. CSR fill — zero atomics, 2M plain 4B random stores
    fill_csr_k<<<(NUM_INTER + 255) / 256, 256, 0, stream>>>(
        inter_u, inter_i, rr, row_start, csr_nbr);

    // 6. mark the needed-z2 set (queried nodes + their neighbors); node-ordered
    //    masked prop keeps locality (R11 lesson: compacted random order regresses)
    mark_k<<<(BATCH * 2 + 255) / 256, 256, 0, stream>>>(
        user_ids, item_ids, row_start, deg, csr_nbr, flag);

    // 7. layer 1 full, unroll-8: zB = z1
    const int per_node_blocks = (N_NODES * 16 + 255) / 256;
    prop_first_k<<<per_node_blocks, 256, 0, stream>>>(
        row_start, csr_nbr, deg, dinv, d2, user_emb, item_emb, zB);

    // 8. layer 2 flag-masked, node-ordered, unroll-8: zA = z2
    prop_masked_k<<<per_node_blocks, 256, 0, stream>>>(
        row_start, csr_nbr, deg, d2, flag, zB, zA);

    // 9. fused: layer-3 pull at queried nodes + layer 0-2 terms + dot product
    fused_score_k<<<(BATCH * 32 + 255) / 256, 256, 0, stream>>>(
        row_start, csr_nbr, deg, dinv, rcp, user_emb, item_emb,
        zB /*z1*/, zA /*z2*/, user_ids, item_ids, w4, out);
}